// Round 9
// baseline (401.597 us; speedup 1.0000x reference)
//
#include <hip/hip_runtime.h>
#include <hip/hip_bf16.h>
#include <cstddef>

// RSAGEConv: 2-layer hetero SAGE (mean agg), N=50000, R=3, E=600000, 128->256->128.
// fp32 in/out. CSR gather aggregation + bf16 MFMA GEMMs.
//
// r19 = r17 (348.7us) + REPAIRED fused GEMM (r18 post-mortem):
//  r18's gemm12 = 119us: Occupancy 8.7% (75.8KB LDS -> <2 blk/CU) + 1.2M LDS
//  bank conflicts (264-pad: 528B stride's built-in block shift cancels spread).
//  FETCH was only 28.9MB -> fusion's memory win is real; fix the execution:
//   - 64-row stripes: grid 782, LDS 36KB (hT 32K + As 4K) -> 4 blk/CU,
//     acc1[4][4]=64 VGPR -> ~16 waves/CU.
//   - hT[64][256] UNPADDED (512B stride) + canonical T2 XOR swizzle
//     byte ^= (row&7)<<4 on write and b128 read (16B-aligned, 8-row spread,
//     2-way residual = free). This is the guide's verified G4 pattern.
//   - ypack in own stripe: uint addr = s<<14 | rel<<12 | (sidx&63)<<6.
//
// gather2 pinned at 70us / FETCH 221MB / 3.2TB/s = random-row floor (r16/r17).
//
// DEAD ENDS (do not revisit):
//  - LDS fp32 atomic accumulation gathers: r13 1300us, r15 1546us.
//  - Global fp32 atomicAdd hot path: CAS loop. (r13)
//  - Per-node/bucket global cursor atomics: same-addr serialization. (r6/r11)
//  - Single-block 64K scan: hidden serial chain. (r12)
//  - VALU trims on memory-floor gathers: no effect. (r16)
//  - 128-row fused stripes @ 2 blk/CU + pad-264: occupancy+conflicts. (r18)

#define NN 50000
#define RR 3
#define EE 600000
#define DIN 128
#define DHID 256
#define DOUT 128
#define NRN (RR * NN)

#define RANGE 256                    // nodes per bin
#define NRANGE ((NN + RANGE - 1) / RANGE)   // 196
#define NBIN (RR * NRANGE)           // 588
#define EPB 4096                     // edges per multisplit block
#define NBLK ((RR * EE + EPB - 1) / EPB)    // 440
#define MAXB2 4096                   // max records per bin (mean 3072, +18 sigma)
#define MTOT (NBIN * NBLK)           // 258720

typedef __hip_bfloat16 bf16;
typedef __hip_bfloat162 bf162;
typedef unsigned short u16;
typedef __attribute__((ext_vector_type(8))) short short8;
typedef __attribute__((ext_vector_type(4))) float floatx4;

__device__ __forceinline__ void async_copy16(const void* g, void* l) {
    __builtin_amdgcn_global_load_lds((const __attribute__((address_space(1))) void*)g,
                                     (__attribute__((address_space(3))) void*)l, 16, 0, 0);
}

// ---------------- fused binhist + prep ----------------
#define PREP_A (NN * 64)
#define PREP_B (256 * 512)
#define PREP_C (512 * 256)
#define PREP_D 384
#define PREP_TOTAL (PREP_A + PREP_B + PREP_C + PREP_D)
#define PREP_BLOCKS ((PREP_TOTAL + 255) / 256)

__global__ __launch_bounds__(256) void hist_prep(const int* __restrict__ dst,
        int* __restrict__ m,
        const float* __restrict__ x,
        const float* __restrict__ Ws1, const float* __restrict__ Wn1,
        const float* __restrict__ b1,
        const float* __restrict__ Ws2, const float* __restrict__ Wn2,
        const float* __restrict__ b2,
        bf16* __restrict__ Abig, bf16* __restrict__ B1t, bf16* __restrict__ B2t,
        float* __restrict__ bias1, float* __restrict__ bias2) {
    __shared__ int lh[NBIN];
    if (blockIdx.x < NBLK) {
        for (int i = threadIdx.x; i < NBIN; i += 256) lh[i] = 0;
        __syncthreads();
        int base = blockIdx.x * EPB;
        int lim = min(EPB, RR * EE - base);
        for (int i = threadIdx.x; i < lim; i += 256) {
            int e = base + i;
            int r = e / EE;
            int d = dst[e];
            atomicAdd(&lh[r * NRANGE + (d >> 8)], 1);
        }
        __syncthreads();
        for (int i = threadIdx.x; i < NBIN; i += 256) m[i * NBLK + blockIdx.x] = lh[i];
        return;
    }
    int idx = (blockIdx.x - NBLK) * 256 + threadIdx.x;
    if (idx < PREP_A) {
        int n = idx >> 6, c2 = idx & 63;
        float2 v = *(const float2*)&x[(size_t)n * DIN + c2 * 2];
        bf162 o; o.x = __float2bfloat16(v.x); o.y = __float2bfloat16(v.y);
        *(bf162*)&Abig[(size_t)n * 512 + c2 * 2] = o;
        return;
    }
    idx -= PREP_A;
    if (idx < PREP_B) {
        int n = idx >> 9, k = idx & 511;
        float v;
        if (k < 128) {
            v = Ws1[(size_t)k * 256 + n]
              + Ws1[(size_t)(128 + k) * 256 + n]
              + Ws1[(size_t)(256 + k) * 256 + n];
        } else {
            int q = k - 128; int r = q >> 7; int kk = q & 127;
            v = Wn1[((size_t)r * 128 + kk) * 256 + n];
        }
        B1t[(size_t)n * 512 + k] = __float2bfloat16(v);
        return;
    }
    idx -= PREP_B;
    if (idx < PREP_C) {
        int n = idx >> 8, k = idx & 255;
        float v;
        if (n < 128) {
            v = Ws2[(size_t)k * 128 + n]
              + Ws2[(size_t)(256 + k) * 128 + n]
              + Ws2[(size_t)(512 + k) * 128 + n];
        } else {
            int q = n - 128; int r = q >> 7; int nn = q & 127;
            v = Wn2[((size_t)r * 256 + k) * 128 + nn];
        }
        B2t[(size_t)n * 256 + k] = __float2bfloat16(v);
        return;
    }
    idx -= PREP_C;
    if (idx < PREP_D) {
        if (idx < 256) {
            bias1[idx] = b1[idx] + b1[256 + idx] + b1[512 + idx];
        } else {
            int j = idx - 256;
            bias2[j] = b2[j] + b2[128 + j] + b2[256 + j];
        }
    }
}

// ---------------- multisplit pass 2: multi-block scan of [NBIN][NBLK] ----------------
__global__ __launch_bounds__(256) void mscan_blocks(int* __restrict__ data,
        int* __restrict__ bsums, int n) {
    int t = threadIdx.x;
    int base = blockIdx.x * 1024 + t * 4;
    int v[4];
    #pragma unroll
    for (int i = 0; i < 4; ++i) v[i] = (base + i < n) ? data[base + i] : 0;
    int s = v[0] + v[1] + v[2] + v[3];
    int lane = t & 63, wid = t >> 6;
    int sc = s;
    #pragma unroll
    for (int d = 1; d < 64; d <<= 1) {
        int tt = __shfl_up(sc, d, 64);
        if (lane >= d) sc += tt;
    }
    __shared__ int wsum[4], woff[4];
    if (lane == 63) wsum[wid] = sc;
    __syncthreads();
    if (t == 0) {
        int a = 0;
        #pragma unroll
        for (int i = 0; i < 4; ++i) { woff[i] = a; a += wsum[i]; }
    }
    __syncthreads();
    int run = sc - s + woff[wid];
    #pragma unroll
    for (int i = 0; i < 4; ++i) {
        if (base + i < n) data[base + i] = run;
        run += v[i];
    }
    if (t == 255) bsums[blockIdx.x] = woff[3] + wsum[3];
}

__global__ __launch_bounds__(256) void mscan_sums(int* __restrict__ bsums, int nb) {
    int t = threadIdx.x;
    int v = (t < nb) ? bsums[t] : 0;
    int lane = t & 63, wid = t >> 6;
    int sc = v;
    #pragma unroll
    for (int d = 1; d < 64; d <<= 1) {
        int tt = __shfl_up(sc, d, 64);
        if (lane >= d) sc += tt;
    }
    __shared__ int wsum[4], woff[4];
    if (lane == 63) wsum[wid] = sc;
    __syncthreads();
    if (t == 0) {
        int a = 0;
        #pragma unroll
        for (int i = 0; i < 4; ++i) { woff[i] = a; a += wsum[i]; }
    }
    __syncthreads();
    if (t < nb) bsums[t] = sc - v + woff[wid];
}

__global__ __launch_bounds__(256) void mscan_fixup(int* __restrict__ m,
        const int* __restrict__ bsums, int* __restrict__ binbase) {
    int i = blockIdx.x * 256 + threadIdx.x;
    if (i < MTOT) {
        int v = m[i] + bsums[i >> 10];
        m[i] = v;
        int q = i / NBLK;
        if (i - q * NBLK == 0) binbase[q] = v;
    }
    if (i == 0) binbase[NBIN] = RR * EE;
}

// ---------------- multisplit pass 3: rank via LDS cursors, block-private segments ----------------
__global__ __launch_bounds__(256) void binscatter(const int* __restrict__ src,
        const int* __restrict__ dst, const int* __restrict__ m,
        unsigned* __restrict__ ebuf) {
    __shared__ int scur[NBIN];
    for (int i = threadIdx.x; i < NBIN; i += 256) scur[i] = m[i * NBLK + blockIdx.x];
    __syncthreads();
    int base = blockIdx.x * EPB;
    int lim = min(EPB, RR * EE - base);
    for (int i = threadIdx.x; i < lim; i += 256) {
        int e = base + i;
        int r = e / EE;
        int d = dst[e];
        int pos = atomicAdd(&scur[r * NRANGE + (d >> 8)], 1);
        ebuf[pos] = ((unsigned)(d & 255) << 16) | (unsigned)src[e];
    }
}

// ---------------- per-bin LDS counting sort -> rowptr + coalesced u16 col ----------------
__global__ __launch_bounds__(256) void binsort(const int* __restrict__ binbase,
        const unsigned* __restrict__ ebuf, u16* __restrict__ col,
        int* __restrict__ rowptr) {
    int b = blockIdx.x;
    int r = b / NRANGE, rb = b - r * NRANGE;
    int node0 = rb * RANGE;
    int nn = min(RANGE, NN - node0);
    int beg = binbase[b], end = binbase[b + 1];
    int cnt = min(end - beg, MAXB2);

    __shared__ unsigned eb[MAXB2];
    __shared__ u16 sb[MAXB2];
    __shared__ int lh[RANGE], lc[RANGE];
    __shared__ int wsum[4], woff[4];

    for (int i = threadIdx.x; i < cnt; i += 256) eb[i] = ebuf[beg + i];
    lh[threadIdx.x] = 0;
    __syncthreads();
    for (int i = threadIdx.x; i < cnt; i += 256) atomicAdd(&lh[eb[i] >> 16], 1);
    __syncthreads();
    {   // exclusive scan of 256 counters (4 waves)
        int t = threadIdx.x, lane = t & 63, wid = t >> 6;
        int v = lh[t];
        int sc = v;
        #pragma unroll
        for (int d = 1; d < 64; d <<= 1) {
            int tt = __shfl_up(sc, d, 64);
            if (lane >= d) sc += tt;
        }
        if (lane == 63) wsum[wid] = sc;
        __syncthreads();
        if (t == 0) {
            int a = 0;
            #pragma unroll
            for (int i = 0; i < 4; ++i) { woff[i] = a; a += wsum[i]; }
        }
        __syncthreads();
        int excl = sc - v + woff[wid];
        lc[t] = excl;
        if (t < nn) rowptr[r * NN + node0 + t] = beg + excl;
        if (t == 0) rowptr[r * NN + node0 + nn] = end;
    }
    __syncthreads();
    for (int i = threadIdx.x; i < cnt; i += 256) {
        unsigned e = eb[i];
        int pos = atomicAdd(&lc[e >> 16], 1);
        sb[pos] = (u16)(e & 0xffffu);
    }
    __syncthreads();
    for (int i = threadIdx.x; i < cnt; i += 256) col[beg + i] = sb[i];
}

__device__ __forceinline__ float bflo(unsigned u) { return __uint_as_float(u << 16); }
__device__ __forceinline__ float bfhi(unsigned u) { return __uint_as_float(u & 0xffff0000u); }

// ---------------- gather1: Abig[n][128+128r..] = mean_{s in col[r,n]} bf16x[s] ----------------
__global__ __launch_bounds__(256) void gather1(const int* __restrict__ rowptr,
        const u16* __restrict__ col, bf16* __restrict__ Abig) {
    int g = blockIdx.x * 4 + (threadIdx.x >> 6);   // r*NN + n
    int lane = threadIdx.x & 63;
    int r = g / NN;
    int n = g - r * NN;
    int beg = rowptr[g], end = rowptr[g + 1];
    const unsigned* xb = (const unsigned*)Abig;    // row stride 256 uints
    float acc0 = 0.f, acc1 = 0.f;
    for (int base = beg; base < end; base += 64) {
        int cnt = min(64, end - base);
        int cidx = (lane < cnt) ? (int)col[base + lane] : 0;
        int j = 0;
        for (; j + 8 <= cnt; j += 8) {
            const unsigned* p0 = xb + (size_t)__builtin_amdgcn_readlane(cidx, j)     * 256;
            const unsigned* p1 = xb + (size_t)__builtin_amdgcn_readlane(cidx, j + 1) * 256;
            const unsigned* p2 = xb + (size_t)__builtin_amdgcn_readlane(cidx, j + 2) * 256;
            const unsigned* p3 = xb + (size_t)__builtin_amdgcn_readlane(cidx, j + 3) * 256;
            const unsigned* p4 = xb + (size_t)__builtin_amdgcn_readlane(cidx, j + 4) * 256;
            const unsigned* p5 = xb + (size_t)__builtin_amdgcn_readlane(cidx, j + 5) * 256;
            const unsigned* p6 = xb + (size_t)__builtin_amdgcn_readlane(cidx, j + 6) * 256;
            const unsigned* p7 = xb + (size_t)__builtin_amdgcn_readlane(cidx, j + 7) * 256;
            unsigned u0 = p0[lane], u1 = p1[lane], u2 = p2[lane], u3 = p3[lane];
            unsigned u4 = p4[lane], u5 = p5[lane], u6 = p6[lane], u7 = p7[lane];
            acc0 += bflo(u0) + bflo(u1) + bflo(u2) + bflo(u3)
                  + bflo(u4) + bflo(u5) + bflo(u6) + bflo(u7);
            acc1 += bfhi(u0) + bfhi(u1) + bfhi(u2) + bfhi(u3)
                  + bfhi(u4) + bfhi(u5) + bfhi(u6) + bfhi(u7);
        }
        for (; j + 4 <= cnt; j += 4) {
            const unsigned* p0 = xb + (size_t)__builtin_amdgcn_readlane(cidx, j)     * 256;
            const unsigned* p1 = xb + (size_t)__builtin_amdgcn_readlane(cidx, j + 1) * 256;
            const unsigned* p2 = xb + (size_t)__builtin_amdgcn_readlane(cidx, j + 2) * 256;
            const unsigned* p3 = xb + (size_t)__builtin_amdgcn_readlane(cidx, j + 3) * 256;
            unsigned u0 = p0[lane], u1 = p1[lane], u2 = p2[lane], u3 = p3[lane];
            acc0 += bflo(u0) + bflo(u1) + bflo(u2) + bflo(u3);
            acc1 += bfhi(u0) + bfhi(u1) + bfhi(u2) + bfhi(u3);
        }
        for (; j < cnt; ++j) {
            const unsigned* p = xb + (size_t)__builtin_amdgcn_readlane(cidx, j) * 256;
            unsigned u = p[lane];
            acc0 += bflo(u);
            acc1 += bfhi(u);
        }
    }
    float inv = 1.0f / fmaxf((float)(end - beg), 1.0f);
    bf162 o;
    o.x = __float2bfloat16(acc0 * inv);
    o.y = __float2bfloat16(acc1 * inv);
    *(bf162*)&Abig[(size_t)n * 512 + 128 + r * 128 + lane * 2] = o;
}

// ---------------- FUSED GEMM v2: 64-row stripes, swizzled LDS h ----------------
// Block s owns rows [64s, 64s+64). 4 waves column-split.
// Phase 1: h[64x256] = relu(A@B1t^T + b1), K=512 -> LDS (XOR-swizzled).
// Phase 2: 4 col-tiles [64x128], K=256 from LDS; ct=0 -> out+b2;
//          ct>=1 -> ypack rel=ct-1 into this stripe's Abig bytes.
__global__ __launch_bounds__(256) void gemm12(bf16* AY,
        const bf16* __restrict__ B1t, const bf16* __restrict__ B2t,
        const float* __restrict__ bias1, const float* __restrict__ bias2,
        float* __restrict__ out) {
    __shared__ bf16 hT[64 * 256];       // 32KB, stride 512B; T2 XOR swizzle
    __shared__ short As[64 * 32];       // 4KB
    char* hTb = (char*)hT;
    const int t = threadIdx.x;
    const int w = t >> 6, lane = t & 63;
    const int m16 = lane & 15, kg = lane >> 4;
    const int s = blockIdx.x;
    const int row0 = s * 64;
    const int ldrow = t >> 2, ldk = (t & 3) * 8;
    const int arow = min(row0 + ldrow, NN - 1);
    const short* Ag = (const short*)AY + (size_t)arow * 512 + ldk;
    short* AsW = &As[(size_t)w * 512];  // wave-uniform base + lane*16B
    const short* B1s = (const short*)B1t;
    const short* B2s = (const short*)B2t;

    // ---- phase 1: h[64x256] = relu(A@B1t^T + bias1), K=512 ----
    floatx4 acc1[4][4] = {};
    for (int kb = 0; kb < 512; kb += 32) {
        async_copy16(Ag + kb, AsW);
        __syncthreads();
        short8 a[4];
        #pragma unroll
        for (int i = 0; i < 4; ++i)
            a[i] = *(const short8*)&As[(i * 16 + m16) * 32 + kg * 8];
        short8 b[4];
        #pragma unroll
        for (int j = 0; j < 4; ++j)
            b[j] = *(const short8*)&B1s[(size_t)(w * 64 + j * 16 + m16) * 512 + kb + kg * 8];
        #pragma unroll
        for (int i = 0; i < 4; ++i)
            #pragma unroll
            for (int j = 0; j < 4; ++j)
                acc1[i][j] = __builtin_amdgcn_mfma_f32_16x16x32_bf16(a[i], b[j], acc1[i][j], 0, 0, 0);
        __syncthreads();
    }
    #pragma unroll
    for (int j = 0; j < 4; ++j) {
        int c = w * 64 + j * 16 + m16;
        float bj = bias1[c];
        #pragma unroll
        for (int i = 0; i < 4; ++i) {
            int rl = i * 16 + kg * 4;
            #pragma unroll
            for (int reg = 0; reg < 4; ++reg) {
                int rr = rl + reg;
                int off = ((rr * 256 + c) * 2) ^ ((rr & 7) << 4);
                *(bf16*)(hTb + off) = __float2bfloat16(fmaxf(acc1[i][j][reg] + bj, 0.f));
            }
        }
    }
    __syncthreads();

    // ---- phase 2: 4 col-tiles of [64x128], K=256 from swizzled LDS ----
    #pragma unroll 1
    for (int ct = 0; ct < 4; ++ct) {
        floatx4 acc[4][2] = {};
        for (int kb = 0; kb < 256; kb += 32) {
            short8 a[4], b[2];
            #pragma unroll
            for (int i = 0; i < 4; ++i) {
                int rr = i * 16 + m16;
                int off = ((rr * 256 + kb + kg * 8) * 2) ^ ((rr & 7) << 4);
                a[i] = *(const short8*)(hTb + off);
            }
            #pragma unroll
            for (int j = 0; j < 2; ++j)
                b[j] = *(const short8*)&B2s[(size_t)(ct * 128 + w * 32 + j * 16 + m16) * 256 + kb + kg * 8];
            #pragma unroll
            for (int i = 0; i < 4; ++i)
                #pragma unroll
                for (int j = 0; j < 2; ++j)
                    acc[i][j] = __builtin_amdgcn_mfma_f32_16x16x32_bf16(a[i], b[j], acc[i][j], 0, 0, 0);
        }
        if (ct == 0) {
            #pragma unroll
            for (int j = 0; j < 2; ++j) {
                int c = w * 32 + j * 16 + m16;
                float bj = bias2[c];
                #pragma unroll
                for (int i = 0; i < 4; ++i) {
                    int rl = i * 16 + kg * 4;
                    #pragma unroll
                    for (int reg = 0; reg < 4; ++reg) {
                        int r = row0 + rl + reg;
                        if (r < NN) out[(size_t)r * DOUT + c] = acc[i][j][reg] + bj;
                    }
                }
            }
        } else {
            int rel = ct - 1;
            bf16* yp = AY + ((size_t)s << 15) + ((size_t)rel << 13);
            #pragma unroll
            for (int j = 0; j < 2; ++j) {
                int c = w * 32 + j * 16 + m16;
                #pragma unroll
                for (int i = 0; i < 4; ++i) {
                    int rl = i * 16 + kg * 4;
                    #pragma unroll
                    for (int reg = 0; reg < 4; ++reg) {
                        if (row0 + rl + reg < NN)
                            yp[((rl + reg) << 7) + c] = __float2bfloat16(acc[i][j][reg]);
                    }
                }
            }
        }
    }
}

// ---------------- gather2: out[n] += sum_r mean_{s in col[r,n]} ypack[r][s] ----------------
// ypack row (rel r, src sidx): uints at ((sidx>>6)<<14) + (r<<12) + ((sidx&63)<<6).
__global__ __launch_bounds__(256) void gather2(const bf16* __restrict__ ypack,
        const int* __restrict__ rowptr, const u16* __restrict__ col,
        float* __restrict__ out) {
    int n = blockIdx.x * 4 + (threadIdx.x >> 6);
    int lane = threadIdx.x & 63;
    float2 acc = *(float2*)&out[(size_t)n * DOUT + lane * 2];
    const unsigned* yb = (const unsigned*)ypack;
    #pragma unroll
    for (int r = 0; r < RR; ++r) {
        int g = r * NN + n;
        int beg = rowptr[g], end = rowptr[g + 1];
        float a0 = 0.f, a1 = 0.f;
        const size_t rbase = (size_t)r << 12;
        for (int base = beg; base < end; base += 64) {
            int cnt = min(64, end - base);
            int cidx = (lane < cnt) ? (int)col[base + lane] : 0;
            int j = 0;
            for (; j + 8 <= cnt; j += 8) {
                int s0 = __builtin_amdgcn_readlane(cidx, j);
                int s1 = __builtin_amdgcn_readlane(cidx, j + 1);
                int s2 = __builtin_amdgcn_readlane(cidx, j + 2);
                int s3 = __builtin_amdgcn_readlane(cidx, j + 3);
                int s4 = __builtin_amdgcn_readlane(cidx, j + 4);
                int s5 = __builtin_amdgcn_readlane(cidx, j + 5);
                int s6 = __builtin_amdgcn_readlane(cidx, j + 6);
                int s7 = __builtin_amdgcn_readlane(cidx, j + 7);
                const unsigned* p0 = yb + rbase + ((size_t)(s0 >> 6) << 14) + ((s0 & 63) << 6);
                const unsigned* p1 = yb + rbase + ((size_t)(s1 >> 6) << 14) + ((s1 & 63) << 6);
                const unsigned* p2 = yb + rbase + ((size_t)(s2 >> 6) << 14) + ((s2 & 63) << 6);
                const unsigned* p3 = yb + rbase + ((size_t)(s3 >> 6) << 14) + ((s3 & 63) << 6);
                const unsigned* p4 = yb + rbase + ((size_t)(s4 >> 6) << 14) + ((s4 & 63) << 6);
                const unsigned* p5 = yb + rbase + ((size_t)(s5 >> 6) << 14) + ((s5 & 63) << 6);
                const unsigned* p6 = yb + rbase + ((size_t)(s6 >> 6) << 14) + ((s6 & 63) << 6);
                const unsigned* p7 = yb + rbase + ((size_t)(s7 >> 6) << 14) + ((s7 & 63) << 6);
                unsigned u0 = p0[lane], u1 = p1[lane], u2 = p2[lane], u3 = p3[lane];
                unsigned u4 = p4[lane], u5 = p5[lane], u6 = p6[lane], u7 = p7[lane];
                a0 += bflo(u0) + bflo(u1) + bflo(u2) + bflo(u3)
                    + bflo(u4) + bflo(u5) + bflo(u6) + bflo(u7);
                a1 += bfhi(u0) + bfhi(u1) + bfhi(u2) + bfhi(u3)
                    + bfhi(u4) + bfhi(u5) + bfhi(u6) + bfhi(u7);
            }
            for (; j < cnt; ++j) {
                int sj = __builtin_amdgcn_readlane(cidx, j);
                const unsigned* p = yb + rbase + ((size_t)(sj >> 6) << 14) + ((sj & 63) << 6);
                unsigned u = p[lane];
                a0 += bflo(u);
                a1 += bfhi(u);
            }
        }
        float inv = 1.0f / fmaxf((float)(end - beg), 1.0f);
        acc.x += a0 * inv;
        acc.y += a1 * inv;
    }
    *(float2*)&out[(size_t)n * DOUT + lane * 2] = acc;
}

// ---------------- launch ----------------
extern "C" void kernel_launch(void* const* d_in, const int* in_sizes, int n_in,
                              void* d_out, int out_size, void* d_ws, size_t ws_size,
                              hipStream_t stream) {
    const float* x       = (const float*)d_in[0];
    const int*   src     = (const int*)  d_in[1];
    const int*   dst     = (const int*)  d_in[2];
    const float* Wself1  = (const float*)d_in[3];
    const float* Wneigh1 = (const float*)d_in[4];
    const float* b1      = (const float*)d_in[5];
    const float* Wself2  = (const float*)d_in[6];
    const float* Wneigh2 = (const float*)d_in[7];
    const float* b2      = (const float*)d_in[8];
    float* out = (float*)d_out;

    char* ws = (char*)d_ws;
    int*      mtx     = (int*)     (ws + 0x0000000ull);   // [588][440] ints (1.03MB)
    int*      binbase = (int*)     (ws + 0x0110000ull);   // [589]
    int*      bsums   = (int*)     (ws + 0x0120000ull);   // [253]
    int*      rowptr  = (int*)     (ws + 0x0140000ull);   // [NRN+1] (600KB)
    float*    bias1   = (float*)   (ws + 0x01E1000ull);
    float*    bias2   = (float*)   (ws + 0x01E2000ull);
    unsigned* ebuf    = (unsigned*)(ws + 0x0200000ull);   // [1.8M] packed (d&255)<<16|src
    bf16*     B1t     = (bf16*)    (ws + 0x0A00000ull);
    bf16*     B2t     = (bf16*)    (ws + 0x0A40000ull);
    bf16*     Abig    = (bf16*)    (ws + 0x0B00000ull);   // [N][512] bf16; ypack overlays per-stripe
    u16*      col     = (u16*)     (ws + 0x5600000ull);   // [1.8M] u16 (3.6MB)

    hist_prep<<<NBLK + PREP_BLOCKS, 256, 0, stream>>>(
        dst, mtx, x, Wself1, Wneigh1, b1, Wself2, Wneigh2, b2,
        Abig, B1t, B2t, bias1, bias2);

    mscan_blocks<<<(MTOT + 1023) / 1024, 256, 0, stream>>>(mtx, bsums, MTOT);
    mscan_sums<<<1, 256, 0, stream>>>(bsums, (MTOT + 1023) / 1024);
    mscan_fixup<<<(MTOT + 255) / 256, 256, 0, stream>>>(mtx, bsums, binbase);
    binscatter<<<NBLK, 256, 0, stream>>>(src, dst, mtx, ebuf);
    binsort<<<NBIN, 256, 0, stream>>>(binbase, ebuf, col, rowptr);

    gather1<<<NRN / 4, 256, 0, stream>>>(rowptr, col, Abig);

    gemm12<<<(NN + 63) / 64, 256, 0, stream>>>(Abig, B1t, B2t, bias1, bias2, out);

    gather2<<<NN / 4, 256, 0, stream>>>(Abig, rowptr, col, out);
}

// Round 10
// 344.051 us; speedup vs baseline: 1.1673x; 1.1673x over previous
//
#include <hip/hip_runtime.h>
#include <hip/hip_bf16.h>
#include <cstddef>

// RSAGEConv: 2-layer hetero SAGE (mean agg), N=50000, R=3, E=600000, 128->256->128.
// fp32 in/out. CSR gather aggregation + bf16 MFMA GEMMs.
//
// r20 = r17 (348.7us, best verified) + two micro-fixes:
//  (1) mscan_fixup DELETED: binscatter/binsort apply +bsums[idx>>10] inline
//      (253-int table, L2-hot). -1 launch, -2MB r/w pass.
//  (2) binsort at 512 threads: halves serial per-block iters over ~3072 recs.
//      All barriers full-block (scan guarded per-thread, not per-barrier).
//
// DEAD ENDS (do not revisit):
//  - FUSED gemm12 (r18 119us, r19 133us vs split ~60us): VGPR 172 caps
//    2 waves/SIMD; barrier-drained K-loop latency chain unexplained by model
//    (133us vs ~25us predicted). Bank conflicts were a red herring (1.2M cyc
//    ~ 2us machine-wide). Split gemm1m/gemm2m is the proven form.
//  - LDS fp32 atomic accumulation gathers: r13 1300us, r15 1546us.
//  - Global fp32 atomicAdd hot path: CAS loop. (r13)
//  - Per-node/bucket global cursor atomics: same-addr serialization. (r6/r11)
//  - Single-block 64K scan: hidden serial chain. (r12)
//  - VALU trims on memory-floor gathers: no effect. (r16)
// FLOORS (measured): gather2 70us / FETCH 221MB / 3.2TB/s random-row; gather1
// same structure. EPB=4096 optimal tested (r17: +41us vs 16384).

#define NN 50000
#define RR 3
#define EE 600000
#define DIN 128
#define DHID 256
#define DOUT 128
#define NRN (RR * NN)

#define RANGE 256                    // nodes per bin
#define NRANGE ((NN + RANGE - 1) / RANGE)   // 196
#define NBIN (RR * NRANGE)           // 588
#define EPB 4096                     // edges per multisplit block
#define NBLK ((RR * EE + EPB - 1) / EPB)    // 440
#define MAXB2 4096                   // max records per bin (mean 3072, +18 sigma)
#define MTOT (NBIN * NBLK)           // 258720

typedef __hip_bfloat16 bf16;
typedef __hip_bfloat162 bf162;
typedef unsigned short u16;
typedef __attribute__((ext_vector_type(8))) short short8;
typedef __attribute__((ext_vector_type(4))) float floatx4;

__device__ __forceinline__ void async_copy16(const void* g, void* l) {
    __builtin_amdgcn_global_load_lds((const __attribute__((address_space(1))) void*)g,
                                     (__attribute__((address_space(3))) void*)l, 16, 0, 0);
}

// ---------------- fused binhist + prep ----------------
#define PREP_A (NN * 64)
#define PREP_B (256 * 512)
#define PREP_C (512 * 256)
#define PREP_D 384
#define PREP_TOTAL (PREP_A + PREP_B + PREP_C + PREP_D)
#define PREP_BLOCKS ((PREP_TOTAL + 255) / 256)

__global__ __launch_bounds__(256) void hist_prep(const int* __restrict__ dst,
        int* __restrict__ m,
        const float* __restrict__ x,
        const float* __restrict__ Ws1, const float* __restrict__ Wn1,
        const float* __restrict__ b1,
        const float* __restrict__ Ws2, const float* __restrict__ Wn2,
        const float* __restrict__ b2,
        bf16* __restrict__ Abig, bf16* __restrict__ B1t, bf16* __restrict__ B2t,
        float* __restrict__ bias1, float* __restrict__ bias2) {
    __shared__ int lh[NBIN];
    if (blockIdx.x < NBLK) {
        for (int i = threadIdx.x; i < NBIN; i += 256) lh[i] = 0;
        __syncthreads();
        int base = blockIdx.x * EPB;
        int lim = min(EPB, RR * EE - base);
        for (int i = threadIdx.x; i < lim; i += 256) {
            int e = base + i;
            int r = e / EE;
            int d = dst[e];
            atomicAdd(&lh[r * NRANGE + (d >> 8)], 1);
        }
        __syncthreads();
        for (int i = threadIdx.x; i < NBIN; i += 256) m[i * NBLK + blockIdx.x] = lh[i];
        return;
    }
    int idx = (blockIdx.x - NBLK) * 256 + threadIdx.x;
    if (idx < PREP_A) {
        int n = idx >> 6, c2 = idx & 63;
        float2 v = *(const float2*)&x[(size_t)n * DIN + c2 * 2];
        bf162 o; o.x = __float2bfloat16(v.x); o.y = __float2bfloat16(v.y);
        *(bf162*)&Abig[(size_t)n * 512 + c2 * 2] = o;
        return;
    }
    idx -= PREP_A;
    if (idx < PREP_B) {
        int n = idx >> 9, k = idx & 511;
        float v;
        if (k < 128) {
            v = Ws1[(size_t)k * 256 + n]
              + Ws1[(size_t)(128 + k) * 256 + n]
              + Ws1[(size_t)(256 + k) * 256 + n];
        } else {
            int q = k - 128; int r = q >> 7; int kk = q & 127;
            v = Wn1[((size_t)r * 128 + kk) * 256 + n];
        }
        B1t[(size_t)n * 512 + k] = __float2bfloat16(v);
        return;
    }
    idx -= PREP_B;
    if (idx < PREP_C) {
        int n = idx >> 8, k = idx & 255;
        float v;
        if (n < 128) {
            v = Ws2[(size_t)k * 128 + n]
              + Ws2[(size_t)(256 + k) * 128 + n]
              + Ws2[(size_t)(512 + k) * 128 + n];
        } else {
            int q = n - 128; int r = q >> 7; int nn = q & 127;
            v = Wn2[((size_t)r * 256 + k) * 128 + nn];
        }
        B2t[(size_t)n * 256 + k] = __float2bfloat16(v);
        return;
    }
    idx -= PREP_C;
    if (idx < PREP_D) {
        if (idx < 256) {
            bias1[idx] = b1[idx] + b1[256 + idx] + b1[512 + idx];
        } else {
            int j = idx - 256;
            bias2[j] = b2[j] + b2[128 + j] + b2[256 + j];
        }
    }
}

// ---------------- multisplit pass 2: multi-block scan of [NBIN][NBLK] ----------------
__global__ __launch_bounds__(256) void mscan_blocks(int* __restrict__ data,
        int* __restrict__ bsums, int n) {
    int t = threadIdx.x;
    int base = blockIdx.x * 1024 + t * 4;
    int v[4];
    #pragma unroll
    for (int i = 0; i < 4; ++i) v[i] = (base + i < n) ? data[base + i] : 0;
    int s = v[0] + v[1] + v[2] + v[3];
    int lane = t & 63, wid = t >> 6;
    int sc = s;
    #pragma unroll
    for (int d = 1; d < 64; d <<= 1) {
        int tt = __shfl_up(sc, d, 64);
        if (lane >= d) sc += tt;
    }
    __shared__ int wsum[4], woff[4];
    if (lane == 63) wsum[wid] = sc;
    __syncthreads();
    if (t == 0) {
        int a = 0;
        #pragma unroll
        for (int i = 0; i < 4; ++i) { woff[i] = a; a += wsum[i]; }
    }
    __syncthreads();
    int run = sc - s + woff[wid];
    #pragma unroll
    for (int i = 0; i < 4; ++i) {
        if (base + i < n) data[base + i] = run;
        run += v[i];
    }
    if (t == 255) bsums[blockIdx.x] = woff[3] + wsum[3];
}

__global__ __launch_bounds__(256) void mscan_sums(int* __restrict__ bsums, int nb) {
    int t = threadIdx.x;
    int v = (t < nb) ? bsums[t] : 0;
    int lane = t & 63, wid = t >> 6;
    int sc = v;
    #pragma unroll
    for (int d = 1; d < 64; d <<= 1) {
        int tt = __shfl_up(sc, d, 64);
        if (lane >= d) sc += tt;
    }
    __shared__ int wsum[4], woff[4];
    if (lane == 63) wsum[wid] = sc;
    __syncthreads();
    if (t == 0) {
        int a = 0;
        #pragma unroll
        for (int i = 0; i < 4; ++i) { woff[i] = a; a += wsum[i]; }
    }
    __syncthreads();
    if (t < nb) bsums[t] = sc - v + woff[wid];
}

// ---------------- multisplit pass 3: rank via LDS cursors, block-private segments ----------------
// scur = locally-scanned m + bsums fixup applied inline (mscan_fixup deleted).
__global__ __launch_bounds__(256) void binscatter(const int* __restrict__ src,
        const int* __restrict__ dst, const int* __restrict__ m,
        const int* __restrict__ bsums, unsigned* __restrict__ ebuf) {
    __shared__ int scur[NBIN];
    for (int i = threadIdx.x; i < NBIN; i += 256) {
        int idx = i * NBLK + blockIdx.x;
        scur[i] = m[idx] + bsums[idx >> 10];
    }
    __syncthreads();
    int base = blockIdx.x * EPB;
    int lim = min(EPB, RR * EE - base);
    for (int i = threadIdx.x; i < lim; i += 256) {
        int e = base + i;
        int r = e / EE;
        int d = dst[e];
        int pos = atomicAdd(&scur[r * NRANGE + (d >> 8)], 1);
        ebuf[pos] = ((unsigned)(d & 255) << 16) | (unsigned)src[e];
    }
}

// ---------------- per-bin LDS counting sort -> rowptr + coalesced u16 col ----------------
// 512 threads (halved serial iters). beg/end from m+bsums inline. Barriers all
// full-block; scan work guarded per-thread (waves 4-7 compute dead values).
__global__ __launch_bounds__(512) void binsort(const int* __restrict__ m,
        const int* __restrict__ bsums, const unsigned* __restrict__ ebuf,
        u16* __restrict__ col, int* __restrict__ rowptr) {
    int b = blockIdx.x;
    int r = b / NRANGE, rb = b - r * NRANGE;
    int node0 = rb * RANGE;
    int nn = min(RANGE, NN - node0);
    int t = threadIdx.x, lane = t & 63, wid = t >> 6;

    __shared__ unsigned eb[MAXB2];
    __shared__ u16 sb[MAXB2];
    __shared__ int lh[RANGE], lc[RANGE];
    __shared__ int wsum[4], woff[4];
    __shared__ int bb[2];

    if (t < 2) {
        int q = b + t;
        bb[t] = (q < NBIN) ? (m[q * NBLK] + bsums[(q * NBLK) >> 10]) : (RR * EE);
    }
    if (t < RANGE) lh[t] = 0;
    __syncthreads();
    int beg = bb[0], end = bb[1];
    int cnt = min(end - beg, MAXB2);

    for (int i = t; i < cnt; i += 512) eb[i] = ebuf[beg + i];
    __syncthreads();
    for (int i = t; i < cnt; i += 512) atomicAdd(&lh[eb[i] >> 16], 1);
    __syncthreads();
    {   // exclusive scan of 256 counters (waves 0-3 carry real data)
        int v = (t < RANGE) ? lh[t] : 0;
        int sc = v;
        #pragma unroll
        for (int d = 1; d < 64; d <<= 1) {
            int tt = __shfl_up(sc, d, 64);
            if (lane >= d) sc += tt;
        }
        if (lane == 63 && wid < 4) wsum[wid] = sc;
        __syncthreads();
        if (t == 0) {
            int a = 0;
            #pragma unroll
            for (int i = 0; i < 4; ++i) { woff[i] = a; a += wsum[i]; }
        }
        __syncthreads();
        if (t < RANGE) {
            int excl = sc - v + woff[wid];
            lc[t] = excl;
            if (t < nn) rowptr[r * NN + node0 + t] = beg + excl;
        }
        if (t == 0) rowptr[r * NN + node0 + nn] = end;
    }
    __syncthreads();
    for (int i = t; i < cnt; i += 512) {
        unsigned e = eb[i];
        int pos = atomicAdd(&lc[e >> 16], 1);
        sb[pos] = (u16)(e & 0xffffu);
    }
    __syncthreads();
    for (int i = t; i < cnt; i += 512) col[beg + i] = sb[i];
}

__device__ __forceinline__ float bflo(unsigned u) { return __uint_as_float(u << 16); }
__device__ __forceinline__ float bfhi(unsigned u) { return __uint_as_float(u & 0xffff0000u); }

// ---------------- gather1: Abig[n][128+128r..] = mean_{s in col[r,n]} bf16x[s] ----------------
__global__ __launch_bounds__(256) void gather1(const int* __restrict__ rowptr,
        const u16* __restrict__ col, bf16* __restrict__ Abig) {
    int g = blockIdx.x * 4 + (threadIdx.x >> 6);   // r*NN + n
    int lane = threadIdx.x & 63;
    int r = g / NN;
    int n = g - r * NN;
    int beg = rowptr[g], end = rowptr[g + 1];
    const unsigned* xb = (const unsigned*)Abig;    // row stride 256 uints
    float acc0 = 0.f, acc1 = 0.f;
    for (int base = beg; base < end; base += 64) {
        int cnt = min(64, end - base);
        int cidx = (lane < cnt) ? (int)col[base + lane] : 0;
        int j = 0;
        for (; j + 8 <= cnt; j += 8) {
            const unsigned* p0 = xb + (size_t)__builtin_amdgcn_readlane(cidx, j)     * 256;
            const unsigned* p1 = xb + (size_t)__builtin_amdgcn_readlane(cidx, j + 1) * 256;
            const unsigned* p2 = xb + (size_t)__builtin_amdgcn_readlane(cidx, j + 2) * 256;
            const unsigned* p3 = xb + (size_t)__builtin_amdgcn_readlane(cidx, j + 3) * 256;
            const unsigned* p4 = xb + (size_t)__builtin_amdgcn_readlane(cidx, j + 4) * 256;
            const unsigned* p5 = xb + (size_t)__builtin_amdgcn_readlane(cidx, j + 5) * 256;
            const unsigned* p6 = xb + (size_t)__builtin_amdgcn_readlane(cidx, j + 6) * 256;
            const unsigned* p7 = xb + (size_t)__builtin_amdgcn_readlane(cidx, j + 7) * 256;
            unsigned u0 = p0[lane], u1 = p1[lane], u2 = p2[lane], u3 = p3[lane];
            unsigned u4 = p4[lane], u5 = p5[lane], u6 = p6[lane], u7 = p7[lane];
            acc0 += bflo(u0) + bflo(u1) + bflo(u2) + bflo(u3)
                  + bflo(u4) + bflo(u5) + bflo(u6) + bflo(u7);
            acc1 += bfhi(u0) + bfhi(u1) + bfhi(u2) + bfhi(u3)
                  + bfhi(u4) + bfhi(u5) + bfhi(u6) + bfhi(u7);
        }
        for (; j + 4 <= cnt; j += 4) {
            const unsigned* p0 = xb + (size_t)__builtin_amdgcn_readlane(cidx, j)     * 256;
            const unsigned* p1 = xb + (size_t)__builtin_amdgcn_readlane(cidx, j + 1) * 256;
            const unsigned* p2 = xb + (size_t)__builtin_amdgcn_readlane(cidx, j + 2) * 256;
            const unsigned* p3 = xb + (size_t)__builtin_amdgcn_readlane(cidx, j + 3) * 256;
            unsigned u0 = p0[lane], u1 = p1[lane], u2 = p2[lane], u3 = p3[lane];
            acc0 += bflo(u0) + bflo(u1) + bflo(u2) + bflo(u3);
            acc1 += bfhi(u0) + bfhi(u1) + bfhi(u2) + bfhi(u3);
        }
        for (; j < cnt; ++j) {
            const unsigned* p = xb + (size_t)__builtin_amdgcn_readlane(cidx, j) * 256;
            unsigned u = p[lane];
            acc0 += bflo(u);
            acc1 += bfhi(u);
        }
    }
    float inv = 1.0f / fmaxf((float)(end - beg), 1.0f);
    bf162 o;
    o.x = __float2bfloat16(acc0 * inv);
    o.y = __float2bfloat16(acc1 * inv);
    *(bf162*)&Abig[(size_t)n * 512 + 128 + r * 128 + lane * 2] = o;
}

// ---------------- MFMA GEMM 1: Abig[N][512](bf16) x B1t[256][512] -> h bf16 [N][256] ----------------
__global__ __launch_bounds__(256) void gemm1m(const bf16* __restrict__ A,
        const bf16* __restrict__ Bt, const float* __restrict__ bias1,
        bf16* __restrict__ h) {
    __shared__ short As[128 * 32];
    __shared__ short Bs[128 * 32];
    const int t = threadIdx.x;
    const int wv = t >> 6, lane = t & 63;
    const int wr = wv >> 1, wc = wv & 1;
    const int m16 = lane & 15, kg = lane >> 4;
    const int row0 = blockIdx.x * 128;
    const int col0 = blockIdx.y * 128;
    const int ldrow = (t >> 2);
    const int ldk = (t & 3) * 8;
    const int arow0 = min(row0 + ldrow, NN - 1);
    const int arow1 = min(row0 + ldrow + 64, NN - 1);
    const short* Ag0 = (const short*)A + (size_t)arow0 * 512 + ldk;
    const short* Ag1 = (const short*)A + (size_t)arow1 * 512 + ldk;
    const short* Bg = (const short*)Bt + (size_t)(col0 + ldrow) * 512 + ldk;
    short* AsW = &As[(size_t)wv * 512];
    short* BsW = &Bs[(size_t)wv * 512];

    floatx4 acc[4][4] = {};
    for (int kb = 0; kb < 512; kb += 32) {
        async_copy16(Ag0 + kb, AsW);
        async_copy16(Ag1 + kb, AsW + 2048);
        async_copy16(Bg + kb, BsW);
        async_copy16(Bg + kb + (size_t)64 * 512, BsW + 2048);
        __syncthreads();
        short8 a[4], b[4];
        #pragma unroll
        for (int i = 0; i < 4; ++i)
            a[i] = *(const short8*)&As[(wr * 64 + i * 16 + m16) * 32 + kg * 8];
        #pragma unroll
        for (int j = 0; j < 4; ++j)
            b[j] = *(const short8*)&Bs[(wc * 64 + j * 16 + m16) * 32 + kg * 8];
        #pragma unroll
        for (int i = 0; i < 4; ++i)
            #pragma unroll
            for (int j = 0; j < 4; ++j)
                acc[i][j] = __builtin_amdgcn_mfma_f32_16x16x32_bf16(a[i], b[j], acc[i][j], 0, 0, 0);
        __syncthreads();
    }
    #pragma unroll
    for (int j = 0; j < 4; ++j) {
        int c = col0 + wc * 64 + j * 16 + m16;
        float bj = bias1[c];
        #pragma unroll
        for (int i = 0; i < 4; ++i) {
            int rb = row0 + wr * 64 + i * 16 + kg * 4;
            #pragma unroll
            for (int reg = 0; reg < 4; ++reg) {
                int r = rb + reg;
                if (r < NN)
                    h[(size_t)r * DHID + c] = __float2bfloat16(fmaxf(acc[i][j][reg] + bj, 0.f));
            }
        }
    }
}

// ---------------- MFMA GEMM 2: h[N][256](bf16) x B2t[512][256] -> out fp32 [N][128] + y bf16 [3][N][128]
__global__ __launch_bounds__(256) void gemm2m(const bf16* __restrict__ A,
        const bf16* __restrict__ Bt, const float* __restrict__ bias2,
        float* __restrict__ out, bf16* __restrict__ y) {
    __shared__ short As[128 * 32];
    __shared__ short Bs[128 * 32];
    const int t = threadIdx.x;
    const int wv = t >> 6, lane = t & 63;
    const int wr = wv >> 1, wc = wv & 1;
    const int m16 = lane & 15, kg = lane >> 4;
    const int row0 = blockIdx.x * 128;
    const int col0 = blockIdx.y * 128;
    const int ldrow = (t >> 2);
    const int ldk = (t & 3) * 8;
    const int arow0 = min(row0 + ldrow, NN - 1);
    const int arow1 = min(row0 + ldrow + 64, NN - 1);
    const short* Ag0 = (const short*)A + (size_t)arow0 * 256 + ldk;
    const short* Ag1 = (const short*)A + (size_t)arow1 * 256 + ldk;
    const short* Bg = (const short*)Bt + (size_t)(col0 + ldrow) * 256 + ldk;
    short* AsW = &As[(size_t)wv * 512];
    short* BsW = &Bs[(size_t)wv * 512];

    floatx4 acc[4][4] = {};
    for (int kb = 0; kb < 256; kb += 32) {
        async_copy16(Ag0 + kb, AsW);
        async_copy16(Ag1 + kb, AsW + 2048);
        async_copy16(Bg + kb, BsW);
        async_copy16(Bg + kb + (size_t)64 * 256, BsW + 2048);
        __syncthreads();
        short8 a[4], b[4];
        #pragma unroll
        for (int i = 0; i < 4; ++i)
            a[i] = *(const short8*)&As[(wr * 64 + i * 16 + m16) * 32 + kg * 8];
        #pragma unroll
        for (int j = 0; j < 4; ++j)
            b[j] = *(const short8*)&Bs[(wc * 64 + j * 16 + m16) * 32 + kg * 8];
        #pragma unroll
        for (int i = 0; i < 4; ++i)
            #pragma unroll
            for (int j = 0; j < 4; ++j)
                acc[i][j] = __builtin_amdgcn_mfma_f32_16x16x32_bf16(a[i], b[j], acc[i][j], 0, 0, 0);
        __syncthreads();
    }
    if (blockIdx.y == 0) {
        #pragma unroll
        for (int j = 0; j < 4; ++j) {
            int c = wc * 64 + j * 16 + m16;
            float bj = bias2[c];
            #pragma unroll
            for (int i = 0; i < 4; ++i) {
                int rb = row0 + wr * 64 + i * 16 + kg * 4;
                #pragma unroll
                for (int reg = 0; reg < 4; ++reg) {
                    int r = rb + reg;
                    if (r < NN) out[(size_t)r * DOUT + c] = acc[i][j][reg] + bj;
                }
            }
        }
    } else {
        int rel = blockIdx.y - 1;
        bf16* yr = y + (size_t)rel * NN * DOUT;
        #pragma unroll
        for (int j = 0; j < 4; ++j) {
            int c = wc * 64 + j * 16 + m16;
            #pragma unroll
            for (int i = 0; i < 4; ++i) {
                int rb = row0 + wr * 64 + i * 16 + kg * 4;
                #pragma unroll
                for (int reg = 0; reg < 4; ++reg) {
                    int r = rb + reg;
                    if (r < NN) yr[(size_t)r * DOUT + c] = __float2bfloat16(acc[i][j][reg]);
                }
            }
        }
    }
}

// ---------------- gather2: out[n] += sum_r mean_{s in col[r,n]} y[r][s] ----------------
__global__ __launch_bounds__(256) void gather2(const bf16* __restrict__ y,
        const int* __restrict__ rowptr, const u16* __restrict__ col,
        float* __restrict__ out) {
    int n = blockIdx.x * 4 + (threadIdx.x >> 6);
    int lane = threadIdx.x & 63;
    float2 acc = *(float2*)&out[(size_t)n * DOUT + lane * 2];
    const unsigned* yb = (const unsigned*)y;   // row stride 64 uints
    #pragma unroll
    for (int r = 0; r < RR; ++r) {
        const unsigned* ybr = yb + (size_t)r * NN * 64;
        int g = r * NN + n;
        int beg = rowptr[g], end = rowptr[g + 1];
        float a0 = 0.f, a1 = 0.f;
        for (int base = beg; base < end; base += 64) {
            int cnt = min(64, end - base);
            int cidx = (lane < cnt) ? (int)col[base + lane] : 0;
            int j = 0;
            for (; j + 8 <= cnt; j += 8) {
                const unsigned* p0 = ybr + (size_t)__builtin_amdgcn_readlane(cidx, j)     * 64;
                const unsigned* p1 = ybr + (size_t)__builtin_amdgcn_readlane(cidx, j + 1) * 64;
                const unsigned* p2 = ybr + (size_t)__builtin_amdgcn_readlane(cidx, j + 2) * 64;
                const unsigned* p3 = ybr + (size_t)__builtin_amdgcn_readlane(cidx, j + 3) * 64;
                const unsigned* p4 = ybr + (size_t)__builtin_amdgcn_readlane(cidx, j + 4) * 64;
                const unsigned* p5 = ybr + (size_t)__builtin_amdgcn_readlane(cidx, j + 5) * 64;
                const unsigned* p6 = ybr + (size_t)__builtin_amdgcn_readlane(cidx, j + 6) * 64;
                const unsigned* p7 = ybr + (size_t)__builtin_amdgcn_readlane(cidx, j + 7) * 64;
                unsigned u0 = p0[lane], u1 = p1[lane], u2 = p2[lane], u3 = p3[lane];
                unsigned u4 = p4[lane], u5 = p5[lane], u6 = p6[lane], u7 = p7[lane];
                a0 += bflo(u0) + bflo(u1) + bflo(u2) + bflo(u3)
                    + bflo(u4) + bflo(u5) + bflo(u6) + bflo(u7);
                a1 += bfhi(u0) + bfhi(u1) + bfhi(u2) + bfhi(u3)
                    + bfhi(u4) + bfhi(u5) + bfhi(u6) + bfhi(u7);
            }
            for (; j + 4 <= cnt; j += 4) {
                const unsigned* p0 = ybr + (size_t)__builtin_amdgcn_readlane(cidx, j)     * 64;
                const unsigned* p1 = ybr + (size_t)__builtin_amdgcn_readlane(cidx, j + 1) * 64;
                const unsigned* p2 = ybr + (size_t)__builtin_amdgcn_readlane(cidx, j + 2) * 64;
                const unsigned* p3 = ybr + (size_t)__builtin_amdgcn_readlane(cidx, j + 3) * 64;
                unsigned u0 = p0[lane], u1 = p1[lane], u2 = p2[lane], u3 = p3[lane];
                a0 += bflo(u0) + bflo(u1) + bflo(u2) + bflo(u3);
                a1 += bfhi(u0) + bfhi(u1) + bfhi(u2) + bfhi(u3);
            }
            for (; j < cnt; ++j) {
                const unsigned* p = ybr + (size_t)__builtin_amdgcn_readlane(cidx, j) * 64;
                unsigned u = p[lane];
                a0 += bflo(u);
                a1 += bfhi(u);
            }
        }
        float inv = 1.0f / fmaxf((float)(end - beg), 1.0f);
        acc.x += a0 * inv;
        acc.y += a1 * inv;
    }
    *(float2*)&out[(size_t)n * DOUT + lane * 2] = acc;
}

// ---------------- launch ----------------
extern "C" void kernel_launch(void* const* d_in, const int* in_sizes, int n_in,
                              void* d_out, int out_size, void* d_ws, size_t ws_size,
                              hipStream_t stream) {
    const float* x       = (const float*)d_in[0];
    const int*   src     = (const int*)  d_in[1];
    const int*   dst     = (const int*)  d_in[2];
    const float* Wself1  = (const float*)d_in[3];
    const float* Wneigh1 = (const float*)d_in[4];
    const float* b1      = (const float*)d_in[5];
    const float* Wself2  = (const float*)d_in[6];
    const float* Wneigh2 = (const float*)d_in[7];
    const float* b2      = (const float*)d_in[8];
    float* out = (float*)d_out;

    char* ws = (char*)d_ws;
    int*      mtx     = (int*)     (ws + 0x0000000ull);   // [588][440] ints (1.03MB)
    int*      bsums   = (int*)     (ws + 0x0120000ull);   // [253]
    int*      rowptr  = (int*)     (ws + 0x0140000ull);   // [NRN+1] (600KB)
    float*    bias1   = (float*)   (ws + 0x01E1000ull);
    float*    bias2   = (float*)   (ws + 0x01E2000ull);
    unsigned* ebuf    = (unsigned*)(ws + 0x0200000ull);   // [1.8M] packed (d&255)<<16|src
    bf16*     B1t     = (bf16*)    (ws + 0x0A00000ull);
    bf16*     B2t     = (bf16*)    (ws + 0x0A40000ull);
    bf16*     Abig    = (bf16*)    (ws + 0x0B00000ull);   // [N][512] bf16 (51.2MB)
    bf16*     y       = (bf16*)    (ws + 0x0B00000ull);   // overlays Abig (dead after gemm1)
    bf16*     h       = (bf16*)    (ws + 0x3C00000ull);   // [N][256] bf16 (25.6MB)
    u16*      col     = (u16*)     (ws + 0x5600000ull);   // [1.8M] u16 (3.6MB)

    hist_prep<<<NBLK + PREP_BLOCKS, 256, 0, stream>>>(
        dst, mtx, x, Wself1, Wneigh1, b1, Wself2, Wneigh2, b2,
        Abig, B1t, B2t, bias1, bias2);

    mscan_blocks<<<(MTOT + 1023) / 1024, 256, 0, stream>>>(mtx, bsums, MTOT);
    mscan_sums<<<1, 256, 0, stream>>>(bsums, (MTOT + 1023) / 1024);
    binscatter<<<NBLK, 256, 0, stream>>>(src, dst, mtx, bsums, ebuf);
    binsort<<<NBIN, 512, 0, stream>>>(mtx, bsums, ebuf, col, rowptr);

    gather1<<<NRN / 4, 256, 0, stream>>>(rowptr, col, Abig);

    gemm1m<<<dim3((NN + 127) / 128, 2), 256, 0, stream>>>(Abig, B1t, bias1, h);
    gemm2m<<<dim3((NN + 127) / 128, 4), 256, 0, stream>>>(h, B2t, bias2, out, y);

    gather2<<<NN / 4, 256, 0, stream>>>(y, rowptr, col, out);
}

// Round 11
// 341.931 us; speedup vs baseline: 1.1745x; 1.0062x over previous
//
#include <hip/hip_runtime.h>
#include <hip/hip_bf16.h>
#include <cstddef>

// RSAGEConv: 2-layer hetero SAGE (mean agg), N=50000, R=3, E=600000, 128->256->128.
// fp32 in/out. CSR gather aggregation + bf16 MFMA GEMMs.
//
// r21 = r20 (344.1us best) + intra-launch overlap of prep with binscatter:
//  - hist split out (440 blocks): scan chain starts ~8us in, not ~30.
//  - prep's 13520 blocks APPENDED to binscatter's grid (one launch, two block
//    roles): scatter blocks are latency-bound, prep blocks bandwidth-bound ->
//    co-resident across CUs, hide each other. No data hazard (prep writes
//    Abig-x/B1t/B2t/bias, read only by later gather1/gemms; scatter reads
//    mtx/bsums/src/dst). Graph capture forbids multi-stream; this is the
//    single-stream equivalent.
//
// DEAD ENDS (do not revisit):
//  - FUSED gemm12 (r18 119us, r19 133us vs split ~60us): VGPR 172 caps waves;
//    direct-from-global B frags + barrier-drained K-loop. Split is proven.
//  - LDS fp32 atomic accumulation gathers: r13 1300us, r15 1546us.
//  - Global fp32 atomicAdd hot path: CAS loop. (r13)
//  - Per-node/bucket global cursor atomics: same-addr serialization. (r6/r11)
//  - Single-block 64K scan: hidden serial chain. (r12)
//  - VALU trims on memory-floor gathers: no effect. (r16)
// FLOORS (measured): gather2 69.4us / FETCH 221MB / 3.2TB/s random-row fabric
// ceiling (Little's law: not latency-bound). gather1 same + 38MB write.
// EPB=4096 optimal tested. Bank-conflict counter <~2us machine-wide (red herring).

#define NN 50000
#define RR 3
#define EE 600000
#define DIN 128
#define DHID 256
#define DOUT 128
#define NRN (RR * NN)

#define RANGE 256                    // nodes per bin
#define NRANGE ((NN + RANGE - 1) / RANGE)   // 196
#define NBIN (RR * NRANGE)           // 588
#define EPB 4096                     // edges per multisplit block
#define NBLK ((RR * EE + EPB - 1) / EPB)    // 440
#define MAXB2 4096                   // max records per bin (mean 3072, +18 sigma)
#define MTOT (NBIN * NBLK)           // 258720

typedef __hip_bfloat16 bf16;
typedef __hip_bfloat162 bf162;
typedef unsigned short u16;
typedef __attribute__((ext_vector_type(8))) short short8;
typedef __attribute__((ext_vector_type(4))) float floatx4;

__device__ __forceinline__ void async_copy16(const void* g, void* l) {
    __builtin_amdgcn_global_load_lds((const __attribute__((address_space(1))) void*)g,
                                     (__attribute__((address_space(3))) void*)l, 16, 0, 0);
}

// ---------------- pass 1: histogram only (440 blocks) ----------------
__global__ __launch_bounds__(256) void hist_only(const int* __restrict__ dst,
                                                 int* __restrict__ m) {
    __shared__ int lh[NBIN];
    for (int i = threadIdx.x; i < NBIN; i += 256) lh[i] = 0;
    __syncthreads();
    int base = blockIdx.x * EPB;
    int lim = min(EPB, RR * EE - base);
    for (int i = threadIdx.x; i < lim; i += 256) {
        int e = base + i;
        int r = e / EE;
        int d = dst[e];
        atomicAdd(&lh[r * NRANGE + (d >> 8)], 1);
    }
    __syncthreads();
    for (int i = threadIdx.x; i < NBIN; i += 256) m[i * NBLK + blockIdx.x] = lh[i];
}

// ---------------- multisplit pass 2: multi-block scan of [NBIN][NBLK] ----------------
__global__ __launch_bounds__(256) void mscan_blocks(int* __restrict__ data,
        int* __restrict__ bsums, int n) {
    int t = threadIdx.x;
    int base = blockIdx.x * 1024 + t * 4;
    int v[4];
    #pragma unroll
    for (int i = 0; i < 4; ++i) v[i] = (base + i < n) ? data[base + i] : 0;
    int s = v[0] + v[1] + v[2] + v[3];
    int lane = t & 63, wid = t >> 6;
    int sc = s;
    #pragma unroll
    for (int d = 1; d < 64; d <<= 1) {
        int tt = __shfl_up(sc, d, 64);
        if (lane >= d) sc += tt;
    }
    __shared__ int wsum[4], woff[4];
    if (lane == 63) wsum[wid] = sc;
    __syncthreads();
    if (t == 0) {
        int a = 0;
        #pragma unroll
        for (int i = 0; i < 4; ++i) { woff[i] = a; a += wsum[i]; }
    }
    __syncthreads();
    int run = sc - s + woff[wid];
    #pragma unroll
    for (int i = 0; i < 4; ++i) {
        if (base + i < n) data[base + i] = run;
        run += v[i];
    }
    if (t == 255) bsums[blockIdx.x] = woff[3] + wsum[3];
}

__global__ __launch_bounds__(256) void mscan_sums(int* __restrict__ bsums, int nb) {
    int t = threadIdx.x;
    int v = (t < nb) ? bsums[t] : 0;
    int lane = t & 63, wid = t >> 6;
    int sc = v;
    #pragma unroll
    for (int d = 1; d < 64; d <<= 1) {
        int tt = __shfl_up(sc, d, 64);
        if (lane >= d) sc += tt;
    }
    __shared__ int wsum[4], woff[4];
    if (lane == 63) wsum[wid] = sc;
    __syncthreads();
    if (t == 0) {
        int a = 0;
        #pragma unroll
        for (int i = 0; i < 4; ++i) { woff[i] = a; a += wsum[i]; }
    }
    __syncthreads();
    if (t < nb) bsums[t] = sc - v + woff[wid];
}

// ---------------- FUSED pass 3: binscatter (440 blocks) || prep (13520 blocks) ----------------
#define PREP_A (NN * 64)
#define PREP_B (256 * 512)
#define PREP_C (512 * 256)
#define PREP_D 384
#define PREP_TOTAL (PREP_A + PREP_B + PREP_C + PREP_D)
#define PREP_BLOCKS ((PREP_TOTAL + 255) / 256)

__global__ __launch_bounds__(256) void scatter_prep(const int* __restrict__ src,
        const int* __restrict__ dst, const int* __restrict__ m,
        const int* __restrict__ bsums, unsigned* __restrict__ ebuf,
        const float* __restrict__ x,
        const float* __restrict__ Ws1, const float* __restrict__ Wn1,
        const float* __restrict__ b1,
        const float* __restrict__ Ws2, const float* __restrict__ Wn2,
        const float* __restrict__ b2,
        bf16* __restrict__ Abig, bf16* __restrict__ B1t, bf16* __restrict__ B2t,
        float* __restrict__ bias1, float* __restrict__ bias2) {
    __shared__ int scur[NBIN];
    if (blockIdx.x < NBLK) {
        for (int i = threadIdx.x; i < NBIN; i += 256) {
            int idx = i * NBLK + blockIdx.x;
            scur[i] = m[idx] + bsums[idx >> 10];
        }
        __syncthreads();
        int base = blockIdx.x * EPB;
        int lim = min(EPB, RR * EE - base);
        for (int i = threadIdx.x; i < lim; i += 256) {
            int e = base + i;
            int r = e / EE;
            int d = dst[e];
            int pos = atomicAdd(&scur[r * NRANGE + (d >> 8)], 1);
            ebuf[pos] = ((unsigned)(d & 255) << 16) | (unsigned)src[e];
        }
        return;
    }
    int idx = (blockIdx.x - NBLK) * 256 + threadIdx.x;
    if (idx < PREP_A) {
        int n = idx >> 6, c2 = idx & 63;
        float2 v = *(const float2*)&x[(size_t)n * DIN + c2 * 2];
        bf162 o; o.x = __float2bfloat16(v.x); o.y = __float2bfloat16(v.y);
        *(bf162*)&Abig[(size_t)n * 512 + c2 * 2] = o;
        return;
    }
    idx -= PREP_A;
    if (idx < PREP_B) {
        int n = idx >> 9, k = idx & 511;
        float v;
        if (k < 128) {
            v = Ws1[(size_t)k * 256 + n]
              + Ws1[(size_t)(128 + k) * 256 + n]
              + Ws1[(size_t)(256 + k) * 256 + n];
        } else {
            int q = k - 128; int r = q >> 7; int kk = q & 127;
            v = Wn1[((size_t)r * 128 + kk) * 256 + n];
        }
        B1t[(size_t)n * 512 + k] = __float2bfloat16(v);
        return;
    }
    idx -= PREP_B;
    if (idx < PREP_C) {
        int n = idx >> 8, k = idx & 255;
        float v;
        if (n < 128) {
            v = Ws2[(size_t)k * 128 + n]
              + Ws2[(size_t)(256 + k) * 128 + n]
              + Ws2[(size_t)(512 + k) * 128 + n];
        } else {
            int q = n - 128; int r = q >> 7; int nn = q & 127;
            v = Wn2[((size_t)r * 256 + k) * 128 + nn];
        }
        B2t[(size_t)n * 256 + k] = __float2bfloat16(v);
        return;
    }
    idx -= PREP_C;
    if (idx < PREP_D) {
        if (idx < 256) {
            bias1[idx] = b1[idx] + b1[256 + idx] + b1[512 + idx];
        } else {
            int j = idx - 256;
            bias2[j] = b2[j] + b2[128 + j] + b2[256 + j];
        }
    }
}

// ---------------- per-bin LDS counting sort -> rowptr + coalesced u16 col ----------------
__global__ __launch_bounds__(512) void binsort(const int* __restrict__ m,
        const int* __restrict__ bsums, const unsigned* __restrict__ ebuf,
        u16* __restrict__ col, int* __restrict__ rowptr) {
    int b = blockIdx.x;
    int r = b / NRANGE, rb = b - r * NRANGE;
    int node0 = rb * RANGE;
    int nn = min(RANGE, NN - node0);
    int t = threadIdx.x, lane = t & 63, wid = t >> 6;

    __shared__ unsigned eb[MAXB2];
    __shared__ u16 sb[MAXB2];
    __shared__ int lh[RANGE], lc[RANGE];
    __shared__ int wsum[4], woff[4];
    __shared__ int bb[2];

    if (t < 2) {
        int q = b + t;
        bb[t] = (q < NBIN) ? (m[q * NBLK] + bsums[(q * NBLK) >> 10]) : (RR * EE);
    }
    if (t < RANGE) lh[t] = 0;
    __syncthreads();
    int beg = bb[0], end = bb[1];
    int cnt = min(end - beg, MAXB2);

    for (int i = t; i < cnt; i += 512) eb[i] = ebuf[beg + i];
    __syncthreads();
    for (int i = t; i < cnt; i += 512) atomicAdd(&lh[eb[i] >> 16], 1);
    __syncthreads();
    {   // exclusive scan of 256 counters (waves 0-3 carry real data)
        int v = (t < RANGE) ? lh[t] : 0;
        int sc = v;
        #pragma unroll
        for (int d = 1; d < 64; d <<= 1) {
            int tt = __shfl_up(sc, d, 64);
            if (lane >= d) sc += tt;
        }
        if (lane == 63 && wid < 4) wsum[wid] = sc;
        __syncthreads();
        if (t == 0) {
            int a = 0;
            #pragma unroll
            for (int i = 0; i < 4; ++i) { woff[i] = a; a += wsum[i]; }
        }
        __syncthreads();
        if (t < RANGE) {
            int excl = sc - v + woff[wid];
            lc[t] = excl;
            if (t < nn) rowptr[r * NN + node0 + t] = beg + excl;
        }
        if (t == 0) rowptr[r * NN + node0 + nn] = end;
    }
    __syncthreads();
    for (int i = t; i < cnt; i += 512) {
        unsigned e = eb[i];
        int pos = atomicAdd(&lc[e >> 16], 1);
        sb[pos] = (u16)(e & 0xffffu);
    }
    __syncthreads();
    for (int i = t; i < cnt; i += 512) col[beg + i] = sb[i];
}

__device__ __forceinline__ float bflo(unsigned u) { return __uint_as_float(u << 16); }
__device__ __forceinline__ float bfhi(unsigned u) { return __uint_as_float(u & 0xffff0000u); }

// ---------------- gather1: Abig[n][128+128r..] = mean_{s in col[r,n]} bf16x[s] ----------------
__global__ __launch_bounds__(256) void gather1(const int* __restrict__ rowptr,
        const u16* __restrict__ col, bf16* __restrict__ Abig) {
    int g = blockIdx.x * 4 + (threadIdx.x >> 6);   // r*NN + n
    int lane = threadIdx.x & 63;
    int r = g / NN;
    int n = g - r * NN;
    int beg = rowptr[g], end = rowptr[g + 1];
    const unsigned* xb = (const unsigned*)Abig;    // row stride 256 uints
    float acc0 = 0.f, acc1 = 0.f;
    for (int base = beg; base < end; base += 64) {
        int cnt = min(64, end - base);
        int cidx = (lane < cnt) ? (int)col[base + lane] : 0;
        int j = 0;
        for (; j + 8 <= cnt; j += 8) {
            const unsigned* p0 = xb + (size_t)__builtin_amdgcn_readlane(cidx, j)     * 256;
            const unsigned* p1 = xb + (size_t)__builtin_amdgcn_readlane(cidx, j + 1) * 256;
            const unsigned* p2 = xb + (size_t)__builtin_amdgcn_readlane(cidx, j + 2) * 256;
            const unsigned* p3 = xb + (size_t)__builtin_amdgcn_readlane(cidx, j + 3) * 256;
            const unsigned* p4 = xb + (size_t)__builtin_amdgcn_readlane(cidx, j + 4) * 256;
            const unsigned* p5 = xb + (size_t)__builtin_amdgcn_readlane(cidx, j + 5) * 256;
            const unsigned* p6 = xb + (size_t)__builtin_amdgcn_readlane(cidx, j + 6) * 256;
            const unsigned* p7 = xb + (size_t)__builtin_amdgcn_readlane(cidx, j + 7) * 256;
            unsigned u0 = p0[lane], u1 = p1[lane], u2 = p2[lane], u3 = p3[lane];
            unsigned u4 = p4[lane], u5 = p5[lane], u6 = p6[lane], u7 = p7[lane];
            acc0 += bflo(u0) + bflo(u1) + bflo(u2) + bflo(u3)
                  + bflo(u4) + bflo(u5) + bflo(u6) + bflo(u7);
            acc1 += bfhi(u0) + bfhi(u1) + bfhi(u2) + bfhi(u3)
                  + bfhi(u4) + bfhi(u5) + bfhi(u6) + bfhi(u7);
        }
        for (; j + 4 <= cnt; j += 4) {
            const unsigned* p0 = xb + (size_t)__builtin_amdgcn_readlane(cidx, j)     * 256;
            const unsigned* p1 = xb + (size_t)__builtin_amdgcn_readlane(cidx, j + 1) * 256;
            const unsigned* p2 = xb + (size_t)__builtin_amdgcn_readlane(cidx, j + 2) * 256;
            const unsigned* p3 = xb + (size_t)__builtin_amdgcn_readlane(cidx, j + 3) * 256;
            unsigned u0 = p0[lane], u1 = p1[lane], u2 = p2[lane], u3 = p3[lane];
            acc0 += bflo(u0) + bflo(u1) + bflo(u2) + bflo(u3);
            acc1 += bfhi(u0) + bfhi(u1) + bfhi(u2) + bfhi(u3);
        }
        for (; j < cnt; ++j) {
            const unsigned* p = xb + (size_t)__builtin_amdgcn_readlane(cidx, j) * 256;
            unsigned u = p[lane];
            acc0 += bflo(u);
            acc1 += bfhi(u);
        }
    }
    float inv = 1.0f / fmaxf((float)(end - beg), 1.0f);
    bf162 o;
    o.x = __float2bfloat16(acc0 * inv);
    o.y = __float2bfloat16(acc1 * inv);
    *(bf162*)&Abig[(size_t)n * 512 + 128 + r * 128 + lane * 2] = o;
}

// ---------------- MFMA GEMM 1: Abig[N][512](bf16) x B1t[256][512] -> h bf16 [N][256] ----------------
__global__ __launch_bounds__(256) void gemm1m(const bf16* __restrict__ A,
        const bf16* __restrict__ Bt, const float* __restrict__ bias1,
        bf16* __restrict__ h) {
    __shared__ short As[128 * 32];
    __shared__ short Bs[128 * 32];
    const int t = threadIdx.x;
    const int wv = t >> 6, lane = t & 63;
    const int wr = wv >> 1, wc = wv & 1;
    const int m16 = lane & 15, kg = lane >> 4;
    const int row0 = blockIdx.x * 128;
    const int col0 = blockIdx.y * 128;
    const int ldrow = (t >> 2);
    const int ldk = (t & 3) * 8;
    const int arow0 = min(row0 + ldrow, NN - 1);
    const int arow1 = min(row0 + ldrow + 64, NN - 1);
    const short* Ag0 = (const short*)A + (size_t)arow0 * 512 + ldk;
    const short* Ag1 = (const short*)A + (size_t)arow1 * 512 + ldk;
    const short* Bg = (const short*)Bt + (size_t)(col0 + ldrow) * 512 + ldk;
    short* AsW = &As[(size_t)wv * 512];
    short* BsW = &Bs[(size_t)wv * 512];

    floatx4 acc[4][4] = {};
    for (int kb = 0; kb < 512; kb += 32) {
        async_copy16(Ag0 + kb, AsW);
        async_copy16(Ag1 + kb, AsW + 2048);
        async_copy16(Bg + kb, BsW);
        async_copy16(Bg + kb + (size_t)64 * 512, BsW + 2048);
        __syncthreads();
        short8 a[4], b[4];
        #pragma unroll
        for (int i = 0; i < 4; ++i)
            a[i] = *(const short8*)&As[(wr * 64 + i * 16 + m16) * 32 + kg * 8];
        #pragma unroll
        for (int j = 0; j < 4; ++j)
            b[j] = *(const short8*)&Bs[(wc * 64 + j * 16 + m16) * 32 + kg * 8];
        #pragma unroll
        for (int i = 0; i < 4; ++i)
            #pragma unroll
            for (int j = 0; j < 4; ++j)
                acc[i][j] = __builtin_amdgcn_mfma_f32_16x16x32_bf16(a[i], b[j], acc[i][j], 0, 0, 0);
        __syncthreads();
    }
    #pragma unroll
    for (int j = 0; j < 4; ++j) {
        int c = col0 + wc * 64 + j * 16 + m16;
        float bj = bias1[c];
        #pragma unroll
        for (int i = 0; i < 4; ++i) {
            int rb = row0 + wr * 64 + i * 16 + kg * 4;
            #pragma unroll
            for (int reg = 0; reg < 4; ++reg) {
                int r = rb + reg;
                if (r < NN)
                    h[(size_t)r * DHID + c] = __float2bfloat16(fmaxf(acc[i][j][reg] + bj, 0.f));
            }
        }
    }
}

// ---------------- MFMA GEMM 2: h[N][256](bf16) x B2t[512][256] -> out fp32 [N][128] + y bf16 [3][N][128]
__global__ __launch_bounds__(256) void gemm2m(const bf16* __restrict__ A,
        const bf16* __restrict__ Bt, const float* __restrict__ bias2,
        float* __restrict__ out, bf16* __restrict__ y) {
    __shared__ short As[128 * 32];
    __shared__ short Bs[128 * 32];
    const int t = threadIdx.x;
    const int wv = t >> 6, lane = t & 63;
    const int wr = wv >> 1, wc = wv & 1;
    const int m16 = lane & 15, kg = lane >> 4;
    const int row0 = blockIdx.x * 128;
    const int col0 = blockIdx.y * 128;
    const int ldrow = (t >> 2);
    const int ldk = (t & 3) * 8;
    const int arow0 = min(row0 + ldrow, NN - 1);
    const int arow1 = min(row0 + ldrow + 64, NN - 1);
    const short* Ag0 = (const short*)A + (size_t)arow0 * 256 + ldk;
    const short* Ag1 = (const short*)A + (size_t)arow1 * 256 + ldk;
    const short* Bg = (const short*)Bt + (size_t)(col0 + ldrow) * 256 + ldk;
    short* AsW = &As[(size_t)wv * 512];
    short* BsW = &Bs[(size_t)wv * 512];

    floatx4 acc[4][4] = {};
    for (int kb = 0; kb < 256; kb += 32) {
        async_copy16(Ag0 + kb, AsW);
        async_copy16(Ag1 + kb, AsW + 2048);
        async_copy16(Bg + kb, BsW);
        async_copy16(Bg + kb + (size_t)64 * 256, BsW + 2048);
        __syncthreads();
        short8 a[4], b[4];
        #pragma unroll
        for (int i = 0; i < 4; ++i)
            a[i] = *(const short8*)&As[(wr * 64 + i * 16 + m16) * 32 + kg * 8];
        #pragma unroll
        for (int j = 0; j < 4; ++j)
            b[j] = *(const short8*)&Bs[(wc * 64 + j * 16 + m16) * 32 + kg * 8];
        #pragma unroll
        for (int i = 0; i < 4; ++i)
            #pragma unroll
            for (int j = 0; j < 4; ++j)
                acc[i][j] = __builtin_amdgcn_mfma_f32_16x16x32_bf16(a[i], b[j], acc[i][j], 0, 0, 0);
        __syncthreads();
    }
    if (blockIdx.y == 0) {
        #pragma unroll
        for (int j = 0; j < 4; ++j) {
            int c = wc * 64 + j * 16 + m16;
            float bj = bias2[c];
            #pragma unroll
            for (int i = 0; i < 4; ++i) {
                int rb = row0 + wr * 64 + i * 16 + kg * 4;
                #pragma unroll
                for (int reg = 0; reg < 4; ++reg) {
                    int r = rb + reg;
                    if (r < NN) out[(size_t)r * DOUT + c] = acc[i][j][reg] + bj;
                }
            }
        }
    } else {
        int rel = blockIdx.y - 1;
        bf16* yr = y + (size_t)rel * NN * DOUT;
        #pragma unroll
        for (int j = 0; j < 4; ++j) {
            int c = wc * 64 + j * 16 + m16;
            #pragma unroll
            for (int i = 0; i < 4; ++i) {
                int rb = row0 + wr * 64 + i * 16 + kg * 4;
                #pragma unroll
                for (int reg = 0; reg < 4; ++reg) {
                    int r = rb + reg;
                    if (r < NN) yr[(size_t)r * DOUT + c] = __float2bfloat16(acc[i][j][reg]);
                }
            }
        }
    }
}

// ---------------- gather2: out[n] += sum_r mean_{s in col[r,n]} y[r][s] ----------------
__global__ __launch_bounds__(256) void gather2(const bf16* __restrict__ y,
        const int* __restrict__ rowptr, const u16* __restrict__ col,
        float* __restrict__ out) {
    int n = blockIdx.x * 4 + (threadIdx.x >> 6);
    int lane = threadIdx.x & 63;
    float2 acc = *(float2*)&out[(size_t)n * DOUT + lane * 2];
    const unsigned* yb = (const unsigned*)y;   // row stride 64 uints
    #pragma unroll
    for (int r = 0; r < RR; ++r) {
        const unsigned* ybr = yb + (size_t)r * NN * 64;
        int g = r * NN + n;
        int beg = rowptr[g], end = rowptr[g + 1];
        float a0 = 0.f, a1 = 0.f;
        for (int base = beg; base < end; base += 64) {
            int cnt = min(64, end - base);
            int cidx = (lane < cnt) ? (int)col[base + lane] : 0;
            int j = 0;
            for (; j + 8 <= cnt; j += 8) {
                const unsigned* p0 = ybr + (size_t)__builtin_amdgcn_readlane(cidx, j)     * 64;
                const unsigned* p1 = ybr + (size_t)__builtin_amdgcn_readlane(cidx, j + 1) * 64;
                const unsigned* p2 = ybr + (size_t)__builtin_amdgcn_readlane(cidx, j + 2) * 64;
                const unsigned* p3 = ybr + (size_t)__builtin_amdgcn_readlane(cidx, j + 3) * 64;
                const unsigned* p4 = ybr + (size_t)__builtin_amdgcn_readlane(cidx, j + 4) * 64;
                const unsigned* p5 = ybr + (size_t)__builtin_amdgcn_readlane(cidx, j + 5) * 64;
                const unsigned* p6 = ybr + (size_t)__builtin_amdgcn_readlane(cidx, j + 6) * 64;
                const unsigned* p7 = ybr + (size_t)__builtin_amdgcn_readlane(cidx, j + 7) * 64;
                unsigned u0 = p0[lane], u1 = p1[lane], u2 = p2[lane], u3 = p3[lane];
                unsigned u4 = p4[lane], u5 = p5[lane], u6 = p6[lane], u7 = p7[lane];
                a0 += bflo(u0) + bflo(u1) + bflo(u2) + bflo(u3)
                    + bflo(u4) + bflo(u5) + bflo(u6) + bflo(u7);
                a1 += bfhi(u0) + bfhi(u1) + bfhi(u2) + bfhi(u3)
                    + bfhi(u4) + bfhi(u5) + bfhi(u6) + bfhi(u7);
            }
            for (; j + 4 <= cnt; j += 4) {
                const unsigned* p0 = ybr + (size_t)__builtin_amdgcn_readlane(cidx, j)     * 64;
                const unsigned* p1 = ybr + (size_t)__builtin_amdgcn_readlane(cidx, j + 1) * 64;
                const unsigned* p2 = ybr + (size_t)__builtin_amdgcn_readlane(cidx, j + 2) * 64;
                const unsigned* p3 = ybr + (size_t)__builtin_amdgcn_readlane(cidx, j + 3) * 64;
                unsigned u0 = p0[lane], u1 = p1[lane], u2 = p2[lane], u3 = p3[lane];
                a0 += bflo(u0) + bflo(u1) + bflo(u2) + bflo(u3);
                a1 += bfhi(u0) + bfhi(u1) + bfhi(u2) + bfhi(u3);
            }
            for (; j < cnt; ++j) {
                const unsigned* p = ybr + (size_t)__builtin_amdgcn_readlane(cidx, j) * 64;
                unsigned u = p[lane];
                a0 += bflo(u);
                a1 += bfhi(u);
            }
        }
        float inv = 1.0f / fmaxf((float)(end - beg), 1.0f);
        acc.x += a0 * inv;
        acc.y += a1 * inv;
    }
    *(float2*)&out[(size_t)n * DOUT + lane * 2] = acc;
}

// ---------------- launch ----------------
extern "C" void kernel_launch(void* const* d_in, const int* in_sizes, int n_in,
                              void* d_out, int out_size, void* d_ws, size_t ws_size,
                              hipStream_t stream) {
    const float* x       = (const float*)d_in[0];
    const int*   src     = (const int*)  d_in[1];
    const int*   dst     = (const int*)  d_in[2];
    const float* Wself1  = (const float*)d_in[3];
    const float* Wneigh1 = (const float*)d_in[4];
    const float* b1      = (const float*)d_in[5];
    const float* Wself2  = (const float*)d_in[6];
    const float* Wneigh2 = (const float*)d_in[7];
    const float* b2      = (const float*)d_in[8];
    float* out = (float*)d_out;

    char* ws = (char*)d_ws;
    int*      mtx     = (int*)     (ws + 0x0000000ull);   // [588][440] ints (1.03MB)
    int*      bsums   = (int*)     (ws + 0x0120000ull);   // [253]
    int*      rowptr  = (int*)     (ws + 0x0140000ull);   // [NRN+1] (600KB)
    float*    bias1   = (float*)   (ws + 0x01E1000ull);
    float*    bias2   = (float*)   (ws + 0x01E2000ull);
    unsigned* ebuf    = (unsigned*)(ws + 0x0200000ull);   // [1.8M] packed (d&255)<<16|src
    bf16*     B1t     = (bf16*)    (ws + 0x0A00000ull);
    bf16*     B2t     = (bf16*)    (ws + 0x0A40000ull);
    bf16*     Abig    = (bf16*)    (ws + 0x0B00000ull);   // [N][512] bf16 (51.2MB)
    bf16*     y       = (bf16*)    (ws + 0x0B00000ull);   // overlays Abig (dead after gemm1)
    bf16*     h       = (bf16*)    (ws + 0x3C00000ull);   // [N][256] bf16 (25.6MB)
    u16*      col     = (u16*)     (ws + 0x5600000ull);   // [1.8M] u16 (3.6MB)

    hist_only<<<NBLK, 256, 0, stream>>>(dst, mtx);
    mscan_blocks<<<(MTOT + 1023) / 1024, 256, 0, stream>>>(mtx, bsums, MTOT);
    mscan_sums<<<1, 256, 0, stream>>>(bsums, (MTOT + 1023) / 1024);

    scatter_prep<<<NBLK + PREP_BLOCKS, 256, 0, stream>>>(
        src, dst, mtx, bsums, ebuf,
        x, Wself1, Wneigh1, b1, Wself2, Wneigh2, b2,
        Abig, B1t, B2t, bias1, bias2);

    binsort<<<NBIN, 512, 0, stream>>>(mtx, bsums, ebuf, col, rowptr);

    gather1<<<NRN / 4, 256, 0, stream>>>(rowptr, col, Abig);

    gemm1m<<<dim3((NN + 127) / 128, 2), 256, 0, stream>>>(Abig, B1t, bias1, h);
    gemm2m<<<dim3((NN + 127) / 128, 4), 256, 0, stream>>>(h, B2t, bias2, out, y);

    gather2<<<NN / 4, 256, 0, stream>>>(y, rowptr, col, out);
}